// Round 19
// baseline (76.524 us; speedup 1.0000x reference)
//
#include <hip/hip_runtime.h>

#define W     768
#define PIX   (768*768)
#define NMAPS 16            // 0..7 anno, 8..15 pred-argmax
#define TROWS 6
#define TPX   (TROWS*W)     // 4608 px per tile
#define NT    (768/TROWS)   // 128 tiles per map
#define NB    (NT-1)        // 127 tile boundaries per map
#define NSEG  (TPX/64)      // 72 wave-segments per tile (12 per row)
#define NIT   (NSEG/4)      // 18 iterations per wave
#define CSLOT 16            // ints per counter slot (64 B line)

// Labels are PACKED everywhere: (label<<2) | cls. Within a component all
// pixels share cls, and min over packed == min over label -> cls bits are
// invariant under atomicMin unions.

__device__ __forceinline__ int find_root_p(volatile int* L, int x) {
    int y = L[x] >> 2;
    while (y != x) { x = y; y = L[x] >> 2; }
    return x;
}

// Unite; true iff a link event occurred (two roots merged). Parents only
// decrease -> acyclic; each index loses rootness at most once, so
// #link events == #merges exactly, independent of atomic ordering.
__device__ __forceinline__ bool unite_p(int* L, int a, int b, int c) {
    volatile int* Lv = L;
    while (true) {
        a = find_root_p(Lv, a);
        b = find_root_p(Lv, b);
        if (a == b) return false;
        if (a > b) { int t = a; a = b; b = t; }
        int old = atomicMin(&L[b], (a << 2) | c);
        if ((old >> 2) == b) return true;
        b = old >> 2;
    }
}

// ---------------- kernels ----------------

// One block per (map, 6-row tile), 256 threads = 4 waves -- the verified
// 45.5us structure (R13 bodies) with DEPTH-2 load prefetch (depth-1 covered
// only ~1 iteration of the ~300-900cy L3/HBM latency). Wave wid owns
// column-segments == wid (mod 4) of EVERY row -> vertical neighbors are
// same-wave; per-run-pair vertical unions fire inside phase A from
// register-carried prev-row state. Counting is runs - links. Phase 3
// touches ONLY tile-boundary rows.
__global__ __launch_bounds__(256) void fused_k(const float* __restrict__ pred,
                                               const int*   __restrict__ anno,
                                               int* __restrict__ labels,
                                               int* __restrict__ counts, int m0) {
    __shared__ int lab[TPX];               // 18 KB packed (label<<2)|cls
    __shared__ int s2[4], s3[4];

    int mc   = blockIdx.x / NT;
    int t    = blockIdx.x - mc * NT;
    int m    = m0 + mc;
    int tid  = threadIdx.x;
    int wid  = tid >> 6;
    int lane = tid & 63;

    unsigned long long lem = (lane == 63) ? ~0ULL : ((2ULL << lane) - 1);  // lanes <= me

    int pc[3] = {0, 0, 0};
    int pm[3] = {0, 0, 0};
    int c2 = 0, c3 = 0;                    // runs - links accumulators

    const int*   asrc = anno + (size_t)m * PIX + (size_t)t * TPX;
    const float* psrc = pred + (size_t)(m < 8 ? 0 : (m - 8)) * 4 * PIX + (size_t)t * TPX;
    bool is_anno = (m < 8);

    // ---- depth-2 prefetch: slots for iterations it and it+1 ----
    int   nab[2] = {0, 0};
    float nb[2][4] = {{0,0,0,0},{0,0,0,0}};
    #pragma unroll
    for (int q = 0; q < 2; ++q) {
        int px = (wid + 4 * q) * 64 + lane;
        if (is_anno) {
            nab[q] = asrc[px];
        } else {
            nb[q][0] = psrc[px];
            nb[q][1] = psrc[(size_t)PIX + px];
            nb[q][2] = psrc[(size_t)2 * PIX + px];
            nb[q][3] = psrc[(size_t)3 * PIX + px];
        }
    }

    #pragma unroll
    for (int it = 0; it < NIT; ++it) {
        const int slot = it & 1;           // static under full unroll
        int seg = wid + 4 * it;
        int px  = seg * 64 + lane;
        int   ca = nab[slot];
        float v0 = nb[slot][0], v1 = nb[slot][1], v2 = nb[slot][2], v3 = nb[slot][3];
        if (it + 2 < NIT) {                // refill freed slot 2 iterations ahead
            int pxn = px + 512;
            if (is_anno) {
                nab[slot] = asrc[pxn];
            } else {
                nb[slot][0] = psrc[pxn];
                nb[slot][1] = psrc[(size_t)PIX + pxn];
                nb[slot][2] = psrc[(size_t)2 * PIX + pxn];
                nb[slot][3] = psrc[(size_t)3 * PIX + pxn];
            }
        }
        int c;
        if (is_anno) {
            c = ca & 3;
        } else {
            c = 0; float bv = v0;           // strict '>' = first-max (jnp.argmax)
            if (v1 > bv) { bv = v1; c = 1; }
            if (v2 > bv) { bv = v2; c = 2; }
            if (v3 > bv) { bv = v3; c = 3; }
        }
        unsigned long long blo = __ballot(c & 1);
        unsigned long long bhi = __ballot(c & 2);
        unsigned long long dif = ((blo ^ (blo << 1)) | (bhi ^ (bhi << 1))) | 1ULL;
        if (lane == 0) {
            c2 += (int)__popcll(dif & bhi & ~blo);
            c3 += (int)__popcll(dif & bhi &  blo);
        }
        int ms = 63 - __clzll(dif & lem);
        lab[px] = ((seg * 64 + ms) << 2) | c;
        const int sl = it % 3;
        if (it >= 3) {
            if ((c & 2) && c == pc[sl]) {
                int mx = ms > pm[sl] ? ms : pm[sl];
                if (lane == mx && unite_p(lab, px - W, px, c)) {
                    if (c == 2) c2--; else c3--;
                }
            }
        }
        pc[sl] = c; pm[sl] = ms;
    }
    __syncthreads();

    if (tid < TROWS * 11) {
        int row = tid / 11, j = tid % 11;
        int px  = row * W + (j + 1) * 64;
        int v = lab[px], c = v & 3;
        if (c & 2) {
            int vl = lab[px - 1];
            if ((vl & 3) == c && unite_p(lab, px - 1, px, c)) {
                if (c == 2) c2--; else c3--;
            }
        }
    }
    __syncthreads();

    int lbase = t * TPX;
    int* gl = labels + (size_t)mc * PIX + lbase;
    #pragma unroll
    for (int q = 0; q < 6; ++q) {
        int it  = (q < 3) ? q : (NIT - 6 + q);   // rows 0 and TROWS-1
        int seg = wid + 4 * it;
        int px  = seg * 64 + lane;
        int v   = lab[px];
        int c   = v & 3;
        int r   = px;
        if (c & 2) r = find_root_p(lab, px);
        int rl = __shfl_up(r, 1);
        gl[px] = ((lbase + r) << 2) | c;         // compressed label (or self)
        if ((c & 2) && (lane == 0 || rl != r))
            gl[r] = ((lbase + r) << 2) | c;      // root self-pointer (idempotent)
    }
    for (int off = 32; off; off >>= 1) {
        c2 += __shfl_down(c2, off, 64);
        c3 += __shfl_down(c3, off, 64);
    }
    if (lane == 0) { s2[wid] = c2; s3[wid] = c3; }
    __syncthreads();
    if (tid == 0) {
        int t2 = s2[0] + s2[1] + s2[2] + s2[3];
        int t3 = s3[0] + s3[1] + s3[2] + s3[3];
        if (t2) atomicAdd(&counts[(m * 2 + 0) * CSLOT], t2);
        if (t3) atomicAdd(&counts[(m * 2 + 1) * CSLOT], t3);
    }
}

// Cross-tile boundary edges on packed labels, 4 columns per thread (int4),
// with LAST-BLOCK FINAL: after this block's atomicSubs land (threadfence),
// a device-scope ticket identifies the globally last boundary block, which
// re-reads the counters coherently (atomicAdd(p,0)) and writes the loss.
// Deterministic: counts' final value is order-independent; the last block
// reads only after all 'total' blocks' subs are fenced-complete.
__global__ __launch_bounds__(256) void boundary_k(int* __restrict__ labels,
                                                  int* __restrict__ counts,
                                                  int* __restrict__ ticket,
                                                  float* __restrict__ out,
                                                  int m0, int total) {
    __shared__ int s2[4], s3[4];
    __shared__ int last_flag;
    const int HM = NB * (W / 4);               // 24384 col-quads per map
    int i    = blockIdx.x * 256 + threadIdx.x;
    int mc   = blockIdx.y;
    int m    = m0 + mc;
    int lane = threadIdx.x & 63;

    int m2 = 0, m3 = 0;
    if (i < HM) {
        int b   = i / (W / 4);
        int col = (i - b * (W / 4)) * 4;
        int* L  = labels + (size_t)mc * PIX;
        int p1  = b * TPX + (TROWS - 1) * W + col;   // tile b, last row
        int p2  = p1 + W;                            // tile b+1, row 0
        int4 va = *(const int4*)&L[p1];
        int4 vb = *(const int4*)&L[p2];
        int paw = __shfl_up(va.w, 1), pbw = __shfl_up(vb.w, 1);
        int a[4] = {va.x, va.y, va.z, va.w};
        int bq[4] = {vb.x, vb.y, vb.z, vb.w};
        int pa = paw, pb = pbw;
        #pragma unroll
        for (int j = 0; j < 4; ++j) {
            int c = a[j] & 3;
            if (c == (bq[j] & 3) && (c & 2)) {
                bool red = (j > 0 || lane > 0) && (pa == a[j]) && (pb == bq[j]);
                if (!red && unite_p(L, p1 + j, p2 + j, c)) {
                    if (c == 2) m2++; else m3++;
                }
            }
            pa = a[j]; pb = bq[j];
        }
    }
    for (int off = 32; off; off >>= 1) {
        m2 += __shfl_down(m2, off, 64);
        m3 += __shfl_down(m3, off, 64);
    }
    int wid = threadIdx.x >> 6;
    if (lane == 0) { s2[wid] = m2; s3[wid] = m3; }
    __syncthreads();
    if (threadIdx.x == 0) {
        int t2 = s2[0] + s2[1] + s2[2] + s2[3];
        int t3 = s3[0] + s3[1] + s3[2] + s3[3];
        if (t2) atomicSub(&counts[(m * 2 + 0) * CSLOT], t2);
        if (t3) atomicSub(&counts[(m * 2 + 1) * CSLOT], t3);
        __threadfence();                         // subs visible before ticket
        int old = atomicAdd(ticket, 1);
        last_flag = (old == total - 1);
    }
    __syncthreads();
    if (last_flag && threadIdx.x < 8) {
        int b = threadIdx.x;                     // one batch per lane
        float a2 = (float)atomicAdd(&counts[(b * 2 + 0) * CSLOT], 0);
        float a3 = (float)atomicAdd(&counts[(b * 2 + 1) * CSLOT], 0);
        float p2 = (float)atomicAdd(&counts[((8 + b) * 2 + 0) * CSLOT], 0);
        float p3 = (float)atomicAdd(&counts[((8 + b) * 2 + 1) * CSLOT], 0);
        float term = (1.0f - 2.0f * fminf(p2, a2) / (a2 + p2))
                   + (1.0f - 2.0f * fminf(p3, a3) / (a3 + p3));
        term += __shfl_down(term, 4, 64);
        term += __shfl_down(term, 2, 64);
        term += __shfl_down(term, 1, 64);
        if (threadIdx.x == 0) out[0] = 0.5f * term;
    }
}

// ---------------- launch ----------------

extern "C" void kernel_launch(void* const* d_in, const int* in_sizes, int n_in,
                              void* d_out, int out_size, void* d_ws, size_t ws_size,
                              hipStream_t stream) {
    const float* pred = (const float*)d_in[0];   // (8,4,1,768,768) f32
    const int*   anno = (const int*)d_in[1];     // (8,1,768,768) i32
    float* out = (float*)d_out;

    int* counts = (int*)d_ws;                    // 32*CSLOT ints = 2 KB
    int* ticket = counts + 32 * CSLOT;           // 1 int, same memset region
    char* base  = (char*)d_ws + 4096;

    const size_t per_map = (size_t)PIX * 4;      // packed labels only
    size_t avail = (ws_size > 4096) ? ws_size - 4096 : 0;
    int K = (int)(avail / per_map);
    if (K > NMAPS) K = NMAPS;
    if (K < 1)     K = 1;    // best effort; needs ~2.4 MB min

    hipMemsetAsync(d_ws, 0, (32 * CSLOT + 16) * sizeof(int), stream);

    const int HM = NB * (W / 4);                 // 24384 col-quads per map
    const int BX = (HM + 255) / 256;             // 96 blocks per map row
    const int total = BX * NMAPS;                // all boundary blocks, all chunks
    for (int m0 = 0; m0 < NMAPS; m0 += K) {      // K=16 -> single pass
        int nm = NMAPS - m0; if (nm > K) nm = K;
        int* labels = (int*)base;
        fused_k   <<<dim3(nm * NT), 256, 0, stream>>>(pred, anno, labels, counts, m0);
        boundary_k<<<dim3(BX, nm), 256, 0, stream>>>(labels, counts, ticket, out, m0, total);
    }
}

// Round 20
// 56.028 us; speedup vs baseline: 1.3658x; 1.3658x over previous
//
#include <hip/hip_runtime.h>

#define W     768
#define PIX   (768*768)
#define NMAPS 16            // 0..7 anno, 8..15 pred-argmax
#define TROWS 6
#define TPX   (TROWS*W)     // 4608 px per tile
#define NT    (768/TROWS)   // 128 tiles per map
#define NB    (NT-1)        // 127 tile boundaries per map
#define NSEG  (TPX/64)      // 72 wave-segments per tile (12 per row)
#define NIT   (NSEG/4)      // 18 iterations per wave
#define CSLOT 16            // ints per counter slot (64 B line)

// Labels are PACKED everywhere: (label<<2) | cls. Within a component all
// pixels share cls, and min over packed == min over label -> cls bits are
// invariant under atomicMin unions.

__device__ __forceinline__ int find_root_p(volatile int* L, int x) {
    int y = L[x] >> 2;
    while (y != x) { x = y; y = L[x] >> 2; }
    return x;
}

// Unite; true iff a link event occurred (two roots merged). Parents only
// decrease -> acyclic; each index loses rootness at most once, so
// #link events == #merges exactly, independent of atomic ordering.
__device__ __forceinline__ bool unite_p(int* L, int a, int b, int c) {
    volatile int* Lv = L;
    while (true) {
        a = find_root_p(Lv, a);
        b = find_root_p(Lv, b);
        if (a == b) return false;
        if (a > b) { int t = a; a = b; b = t; }
        int old = atomicMin(&L[b], (a << 2) | c);
        if ((old >> 2) == b) return true;
        b = old >> 2;
    }
}

// ---------------- kernels ----------------

// One block per (map, 6-row tile), 256 threads = 4 waves -- the verified
// best configuration (R18: 56.08us total; fused_k 45.5us). Wave wid owns
// column-segments == wid (mod 4) of EVERY row -> vertical neighbors are
// same-wave; per-run-pair vertical unions fire inside phase A from
// register-carried prev-row state. Counting is runs - links: run counts
// from popcounts of ballot run-break masks; every successful union
// decrements. Phase 3 touches ONLY tile-boundary rows (compressed labels
// + boundary-reachable root self-pointers).
// NOTE (session record): ten structural variants (R9-R19) bracketed this
// kernel at 45.5-49.5us -- latency-structural plateau of the LDS
// union-find family (serial per-wave spine + divergent LDS pointer-chase
// at the 8-block/CU LDS occupancy cap), all pipes <40% busy. Per-block
// __threadfence() in a wide dispatch costs ~20us total (R19) -- avoid.
__global__ __launch_bounds__(256) void fused_k(const float* __restrict__ pred,
                                               const int*   __restrict__ anno,
                                               int* __restrict__ labels,
                                               int* __restrict__ counts, int m0) {
    __shared__ int lab[TPX];               // 18 KB packed (label<<2)|cls
    __shared__ int s2[4], s3[4];

    int mc   = blockIdx.x / NT;
    int t    = blockIdx.x - mc * NT;
    int m    = m0 + mc;
    int tid  = threadIdx.x;
    int wid  = tid >> 6;
    int lane = tid & 63;

    unsigned long long lem = (lane == 63) ? ~0ULL : ((2ULL << lane) - 1);  // lanes <= me

    int pc[3] = {0, 0, 0};
    int pm[3] = {0, 0, 0};
    int c2 = 0, c3 = 0;                    // runs - links accumulators

    const int*   asrc = anno + (size_t)m * PIX + (size_t)t * TPX;
    const float* psrc = pred + (size_t)(m < 8 ? 0 : (m - 8)) * 4 * PIX + (size_t)t * TPX;
    bool is_anno = (m < 8);

    int   na = 0;
    float nv0 = 0.f, nv1 = 0.f, nv2 = 0.f, nv3 = 0.f;
    {
        int px = wid * 64 + lane;
        if (is_anno) {
            na = asrc[px];
        } else {
            nv0 = psrc[px];
            nv1 = psrc[(size_t)PIX + px];
            nv2 = psrc[(size_t)2 * PIX + px];
            nv3 = psrc[(size_t)3 * PIX + px];
        }
    }

    #pragma unroll
    for (int it = 0; it < NIT; ++it) {
        int seg = wid + 4 * it;
        int px  = seg * 64 + lane;
        int   ca = na;
        float v0 = nv0, v1 = nv1, v2 = nv2, v3 = nv3;
        if (it + 1 < NIT) {
            int pxn = px + 256;
            if (is_anno) {
                na = asrc[pxn];
            } else {
                nv0 = psrc[pxn];
                nv1 = psrc[(size_t)PIX + pxn];
                nv2 = psrc[(size_t)2 * PIX + pxn];
                nv3 = psrc[(size_t)3 * PIX + pxn];
            }
        }
        int c;
        if (is_anno) {
            c = ca & 3;
        } else {
            c = 0; float bv = v0;           // strict '>' = first-max (jnp.argmax)
            if (v1 > bv) { bv = v1; c = 1; }
            if (v2 > bv) { bv = v2; c = 2; }
            if (v3 > bv) { bv = v3; c = 3; }
        }
        unsigned long long blo = __ballot(c & 1);
        unsigned long long bhi = __ballot(c & 2);
        unsigned long long dif = ((blo ^ (blo << 1)) | (bhi ^ (bhi << 1))) | 1ULL;
        if (lane == 0) {
            c2 += (int)__popcll(dif & bhi & ~blo);
            c3 += (int)__popcll(dif & bhi &  blo);
        }
        int ms = 63 - __clzll(dif & lem);
        lab[px] = ((seg * 64 + ms) << 2) | c;
        const int sl = it % 3;
        if (it >= 3) {
            if ((c & 2) && c == pc[sl]) {
                int mx = ms > pm[sl] ? ms : pm[sl];
                if (lane == mx && unite_p(lab, px - W, px, c)) {
                    if (c == 2) c2--; else c3--;
                }
            }
        }
        pc[sl] = c; pm[sl] = ms;
    }
    __syncthreads();

    if (tid < TROWS * 11) {
        int row = tid / 11, j = tid % 11;
        int px  = row * W + (j + 1) * 64;
        int v = lab[px], c = v & 3;
        if (c & 2) {
            int vl = lab[px - 1];
            if ((vl & 3) == c && unite_p(lab, px - 1, px, c)) {
                if (c == 2) c2--; else c3--;
            }
        }
    }
    __syncthreads();

    int lbase = t * TPX;
    int* gl = labels + (size_t)mc * PIX + lbase;
    #pragma unroll
    for (int q = 0; q < 6; ++q) {
        int it  = (q < 3) ? q : (NIT - 6 + q);   // rows 0 and TROWS-1
        int seg = wid + 4 * it;
        int px  = seg * 64 + lane;
        int v   = lab[px];
        int c   = v & 3;
        int r   = px;
        if (c & 2) r = find_root_p(lab, px);
        int rl = __shfl_up(r, 1);
        gl[px] = ((lbase + r) << 2) | c;         // compressed label (or self)
        if ((c & 2) && (lane == 0 || rl != r))
            gl[r] = ((lbase + r) << 2) | c;      // root self-pointer (idempotent)
    }
    for (int off = 32; off; off >>= 1) {
        c2 += __shfl_down(c2, off, 64);
        c3 += __shfl_down(c3, off, 64);
    }
    if (lane == 0) { s2[wid] = c2; s3[wid] = c3; }
    __syncthreads();
    if (tid == 0) {
        int t2 = s2[0] + s2[1] + s2[2] + s2[3];
        int t3 = s3[0] + s3[1] + s3[2] + s3[3];
        if (t2) atomicAdd(&counts[(m * 2 + 0) * CSLOT], t2);
        if (t3) atomicAdd(&counts[(m * 2 + 1) * CSLOT], t3);
    }
}

// Cross-tile boundary edges on packed labels, 4 columns per thread (int4).
// Run-dedup: skip a union when the packed-value pair equals the previous
// column's pair (same run pair -> redundant; dedup is an optimization only,
// duplicate unions are idempotent and count only real merges).
// blockIdx.y = map -> counts index is block-uniform.
__global__ __launch_bounds__(256) void boundary_k(int* __restrict__ labels,
                                                  int* __restrict__ counts, int m0) {
    __shared__ int s2[4], s3[4];
    const int HM = NB * (W / 4);               // 24384 col-quads per map
    int i    = blockIdx.x * 256 + threadIdx.x;
    int mc   = blockIdx.y;
    int m    = m0 + mc;
    int lane = threadIdx.x & 63;

    int m2 = 0, m3 = 0;
    if (i < HM) {
        int b   = i / (W / 4);
        int col = (i - b * (W / 4)) * 4;
        int* L  = labels + (size_t)mc * PIX;
        int p1  = b * TPX + (TROWS - 1) * W + col;   // tile b, last row
        int p2  = p1 + W;                            // tile b+1, row 0
        int4 va = *(const int4*)&L[p1];
        int4 vb = *(const int4*)&L[p2];
        int paw = __shfl_up(va.w, 1), pbw = __shfl_up(vb.w, 1);
        int a[4] = {va.x, va.y, va.z, va.w};
        int bq[4] = {vb.x, vb.y, vb.z, vb.w};
        int pa = paw, pb = pbw;
        #pragma unroll
        for (int j = 0; j < 4; ++j) {
            int c = a[j] & 3;
            if (c == (bq[j] & 3) && (c & 2)) {
                bool red = (j > 0 || lane > 0) && (pa == a[j]) && (pb == bq[j]);
                if (!red && unite_p(L, p1 + j, p2 + j, c)) {
                    if (c == 2) m2++; else m3++;
                }
            }
            pa = a[j]; pb = bq[j];
        }
    }
    for (int off = 32; off; off >>= 1) {
        m2 += __shfl_down(m2, off, 64);
        m3 += __shfl_down(m3, off, 64);
    }
    int wid = threadIdx.x >> 6;
    if (lane == 0) { s2[wid] = m2; s3[wid] = m3; }
    __syncthreads();
    if (threadIdx.x == 0) {
        int t2 = s2[0] + s2[1] + s2[2] + s2[3];
        int t3 = s3[0] + s3[1] + s3[2] + s3[3];
        if (t2) atomicSub(&counts[(m * 2 + 0) * CSLOT], t2);
        if (t3) atomicSub(&counts[(m * 2 + 1) * CSLOT], t3);
    }
}

__global__ void final_k(const int* __restrict__ counts, float* __restrict__ out) {
    float s = 0.0f;
    for (int b = 0; b < 8; ++b) {
        float a2 = (float)counts[(b * 2 + 0) * CSLOT];
        float a3 = (float)counts[(b * 2 + 1) * CSLOT];
        float p2 = (float)counts[((8 + b) * 2 + 0) * CSLOT];
        float p3 = (float)counts[((8 + b) * 2 + 1) * CSLOT];
        float t2 = 1.0f - 2.0f * fminf(p2, a2) / (a2 + p2);
        float t3 = 1.0f - 2.0f * fminf(p3, a3) / (a3 + p3);
        s += t2 + t3;
    }
    out[0] = 0.5f * s;
}

// ---------------- launch ----------------

extern "C" void kernel_launch(void* const* d_in, const int* in_sizes, int n_in,
                              void* d_out, int out_size, void* d_ws, size_t ws_size,
                              hipStream_t stream) {
    const float* pred = (const float*)d_in[0];   // (8,4,1,768,768) f32
    const int*   anno = (const int*)d_in[1];     // (8,1,768,768) i32
    float* out = (float*)d_out;

    int* counts = (int*)d_ws;                    // 32*CSLOT ints = 2 KB
    char* base  = (char*)d_ws + 4096;

    const size_t per_map = (size_t)PIX * 4;      // packed labels only
    size_t avail = (ws_size > 4096) ? ws_size - 4096 : 0;
    int K = (int)(avail / per_map);
    if (K > NMAPS) K = NMAPS;
    if (K < 1)     K = 1;    // best effort; needs ~2.4 MB min

    hipMemsetAsync(counts, 0, 32 * CSLOT * sizeof(int), stream);

    const int HM = NB * (W / 4);                 // 24384 col-quads per map
    for (int m0 = 0; m0 < NMAPS; m0 += K) {      // K=16 -> single pass
        int nm = NMAPS - m0; if (nm > K) nm = K;
        int* labels = (int*)base;
        fused_k   <<<dim3(nm * NT), 256, 0, stream>>>(pred, anno, labels, counts, m0);
        boundary_k<<<dim3((HM + 255) / 256, nm), 256, 0, stream>>>(labels, counts, m0);
    }
    final_k<<<1, 1, 0, stream>>>(counts, out);
}